// Round 2
// baseline (176.138 us; speedup 1.0000x reference)
//
#include <hip/hip_runtime.h>
#include <hip/hip_bf16.h>

#define B_  4
#define LQ  512
#define LK  512
#define D_  128
#define H_  128
#define TQ  4

// tanh(x) = 1 - 2/(exp(2x)+1); saturates correctly at +-1 for large |x| (no inf/inf NaN)
__device__ __forceinline__ float fast_tanh(float x) {
  float e = __expf(2.0f * x);
  return 1.0f - __fdividef(2.0f, e + 1.0f);
}

// One block per output row (128 threads). Rows [0,2048) -> q_proj, [2048,4096) -> k_proj.
__global__ __launch_bounds__(128) void proj_kernel(
    const float* __restrict__ queries, const float* __restrict__ keys,
    const float* __restrict__ Wq, const float* __restrict__ Wk,
    float* __restrict__ qproj, float* __restrict__ kproj) {
  __shared__ float xrow[D_];
  int row = blockIdx.x;
  const float* X; const float* W; float* Y; int r;
  if (row < B_ * LQ) { X = queries; W = Wq; Y = qproj; r = row; }
  else               { X = keys;    W = Wk; Y = kproj; r = row - B_ * LQ; }
  int h = threadIdx.x;
  xrow[h] = X[r * D_ + h];
  __syncthreads();
  float acc = 0.f;
  #pragma unroll 16
  for (int d = 0; d < D_; ++d) acc += xrow[d] * W[d * H_ + h];  // lanes->consecutive h: coalesced
  Y[r * H_ + h] = acc;
}

// One block per (batch, 4 q-rows). 256 threads = 4 waves.
__global__ __launch_bounds__(256) void attn_kernel(
    const float* __restrict__ qproj, const float* __restrict__ kproj,
    const float* __restrict__ values, const int* __restrict__ vlen_arr,
    const float* __restrict__ wv, const float* __restrict__ Wo,
    float* __restrict__ out) {
  int b  = blockIdx.y;
  int q0 = blockIdx.x * TQ;
  int tid = threadIdx.x;

  __shared__ float s_q[TQ][H_];     // 2 KB
  __shared__ float s_wv[H_];        // 0.5 KB
  __shared__ float s_sc[TQ][LK];    // 8 KB
  __shared__ float s_o[TQ][D_];     // 2 KB

  for (int i = tid; i < TQ * H_; i += 256)
    s_q[i >> 7][i & 127] = qproj[(size_t)(b * LQ + q0 + (i >> 7)) * H_ + (i & 127)];
  if (tid < H_) s_wv[tid] = wv[tid];
  __syncthreads();
  int vlen = vlen_arr[b];

  const float4* wv4 = (const float4*)s_wv;

  // ---- scores: each thread owns one k column, accumulates TQ q-rows ----
  for (int kbase = 0; kbase < LK; kbase += 256) {
    int k = kbase + tid;
    const float4* krow = (const float4*)(kproj + (size_t)(b * LK + k) * H_);
    float acc[TQ];
    #pragma unroll
    for (int ql = 0; ql < TQ; ++ql) acc[ql] = 0.f;
    #pragma unroll 4
    for (int h4 = 0; h4 < H_ / 4; ++h4) {
      float4 kv = krow[h4];      // per-lane row: L1/L2-resident, line fully consumed
      float4 w4 = wv4[h4];       // LDS broadcast
      #pragma unroll
      for (int ql = 0; ql < TQ; ++ql) {
        float4 q4 = ((const float4*)s_q[ql])[h4];  // LDS broadcast
        acc[ql] += w4.x * fast_tanh(q4.x + kv.x)
                 + w4.y * fast_tanh(q4.y + kv.y)
                 + w4.z * fast_tanh(q4.z + kv.z)
                 + w4.w * fast_tanh(q4.w + kv.w);
      }
    }
    #pragma unroll
    for (int ql = 0; ql < TQ; ++ql)
      s_sc[ql][k] = (k < vlen) ? acc[ql] : -1.0e6f;
  }
  __syncthreads();

  // ---- masked softmax: wave w handles q-row w ----
  int wave = tid >> 6, lane = tid & 63;
  {
    float m = -3.0e38f;
    #pragma unroll
    for (int j = 0; j < LK / 64; ++j) m = fmaxf(m, s_sc[wave][lane + j * 64]);
    #pragma unroll
    for (int off = 32; off; off >>= 1) m = fmaxf(m, __shfl_xor(m, off));
    float sum = 0.f;
    float vals[LK / 64];
    #pragma unroll
    for (int j = 0; j < LK / 64; ++j) {
      float e = __expf(s_sc[wave][lane + j * 64] - m);  // masked -> exp(-1e6-m) underflows to 0
      vals[j] = e;
      sum += e;
    }
    #pragma unroll
    for (int off = 32; off; off >>= 1) sum += __shfl_xor(sum, off);
    float inv = __fdividef(1.f, sum);
    #pragma unroll
    for (int j = 0; j < LK / 64; ++j) s_sc[wave][lane + j * 64] = vals[j] * inv;
  }
  __syncthreads();

  // ---- PV: wave w handles q-row w; lane covers 2 d (float2, coalesced) ----
  {
    const float2* vrow = (const float2*)(values + (size_t)b * LK * D_);
    float2 acc2 = {0.f, 0.f};
    for (int k = 0; k < LK; k += 4) {
      float4 sc4 = *((const float4*)&s_sc[wave][k]);  // LDS broadcast
      float2 v0 = vrow[(size_t)(k + 0) * 64 + lane];
      float2 v1 = vrow[(size_t)(k + 1) * 64 + lane];
      float2 v2 = vrow[(size_t)(k + 2) * 64 + lane];
      float2 v3 = vrow[(size_t)(k + 3) * 64 + lane];
      acc2.x += sc4.x * v0.x + sc4.y * v1.x + sc4.z * v2.x + sc4.w * v3.x;
      acc2.y += sc4.x * v0.y + sc4.y * v1.y + sc4.z * v2.y + sc4.w * v3.y;
    }
    s_o[wave][2 * lane]     = acc2.x;
    s_o[wave][2 * lane + 1] = acc2.y;
  }
  __syncthreads();

  // ---- output projection: out[b][q0+ql][h] = sum_d s_o[ql][d] * Wo[d][h] ----
  for (int i = tid; i < TQ * H_; i += 256) {
    int ql = i >> 7, h = i & 127;
    float acc = 0.f;
    #pragma unroll 8
    for (int d = 0; d < D_; ++d) acc += s_o[ql][d] * Wo[d * H_ + h];  // coalesced, L2-hot
    out[(size_t)(b * LQ + q0 + ql) * H_ + h] = acc;
  }
}

extern "C" void kernel_launch(void* const* d_in, const int* in_sizes, int n_in,
                              void* d_out, int out_size, void* d_ws, size_t ws_size,
                              hipStream_t stream) {
  const float* queries = (const float*)d_in[0];
  const float* keys    = (const float*)d_in[1];
  const float* values  = (const float*)d_in[2];
  const int*   vlen    = (const int*)d_in[3];
  const float* Wq      = (const float*)d_in[4];
  const float* Wk      = (const float*)d_in[5];
  const float* wv      = (const float*)d_in[6];
  const float* Wo      = (const float*)d_in[7];
  float* out = (float*)d_out;

  // workspace: q_proj (1 MB) + k_proj (1 MB); fully overwritten every call
  float* qproj = (float*)d_ws;
  float* kproj = qproj + (size_t)B_ * LQ * H_;

  proj_kernel<<<dim3(B_ * (LQ + LK)), 128, 0, stream>>>(queries, keys, Wq, Wk, qproj, kproj);
  attn_kernel<<<dim3(LQ / TQ, B_), 256, 0, stream>>>(qproj, kproj, values, vlen, wv, Wo, out);
}

// Round 3
// 121.730 us; speedup vs baseline: 1.4470x; 1.4470x over previous
//
#include <hip/hip_runtime.h>
#include <hip/hip_bf16.h>

#define B_  4
#define LQ  512
#define LK  512
#define D_  128
#define H_  128
#define TQ  2          // q-rows per attn block

#define TWO_LOG2E 2.885390081777927f   // 2*log2(e)
#define LOG2E     1.442695040888963f

__device__ __forceinline__ float fexp2(float x) {
#if __has_builtin(__builtin_amdgcn_exp2f)
  return __builtin_amdgcn_exp2f(x);     // v_exp_f32 (exp2 native)
#else
  return exp2f(x);
#endif
}
__device__ __forceinline__ float frcp(float x) {
#if __has_builtin(__builtin_amdgcn_rcpf)
  return __builtin_amdgcn_rcpf(x);      // v_rcp_f32
#else
  return __fdividef(1.0f, x);
#endif
}

// 8 rows per block, 256 threads. Rows [0, B*LQ) -> qproj, rest -> kproj.
// Outputs pre-scaled by 2*log2(e) so the score kernel can feed v_exp directly.
__global__ __launch_bounds__(256) void proj_kernel(
    const float* __restrict__ queries, const float* __restrict__ keys,
    const float* __restrict__ Wq, const float* __restrict__ Wk,
    float* __restrict__ qproj, float* __restrict__ kproj) {
  __shared__ float s_x[8][D_];
  int r0 = blockIdx.x * 8;
  const float* X; const float* W; float* Y; int rb;
  if (r0 < B_ * LQ) { X = queries; W = Wq; Y = qproj; rb = r0; }
  else              { X = keys;    W = Wk; Y = kproj; rb = r0 - B_ * LQ; }
  int tid = threadIdx.x;
  for (int i = tid; i < 8 * D_; i += 256)
    s_x[i >> 7][i & 127] = X[(size_t)(rb + (i >> 7)) * D_ + (i & 127)];
  __syncthreads();
  int h = tid & 127, rh = tid >> 7;    // rh selects rows rh*4 .. rh*4+3
  float a0 = 0.f, a1 = 0.f, a2 = 0.f, a3 = 0.f;
  #pragma unroll 8
  for (int d = 0; d < D_; ++d) {
    float w = W[d * H_ + h];           // coalesced; W is L2-hot (64 KB)
    a0 += s_x[rh * 4 + 0][d] * w;      // LDS broadcasts
    a1 += s_x[rh * 4 + 1][d] * w;
    a2 += s_x[rh * 4 + 2][d] * w;
    a3 += s_x[rh * 4 + 3][d] * w;
  }
  Y[(size_t)(rb + rh * 4 + 0) * H_ + h] = a0 * TWO_LOG2E;
  Y[(size_t)(rb + rh * 4 + 1) * H_ + h] = a1 * TWO_LOG2E;
  Y[(size_t)(rb + rh * 4 + 2) * H_ + h] = a2 * TWO_LOG2E;
  Y[(size_t)(rb + rh * 4 + 3) * H_ + h] = a3 * TWO_LOG2E;
}

// One block per (batch, TQ q-rows). 256 threads = 4 waves.
__global__ __launch_bounds__(256) void attn_kernel(
    const float* __restrict__ qproj, const float* __restrict__ kproj,
    const float* __restrict__ values, const int* __restrict__ vlen_arr,
    const float* __restrict__ wv, const float* __restrict__ Wo,
    float* __restrict__ out) {
  int b  = blockIdx.y;
  int q0 = blockIdx.x * TQ;
  int tid = threadIdx.x;

  __shared__ float s_q[TQ][H_];        // pre-scaled q rows
  __shared__ float s_wv[H_];
  __shared__ float s_sc[TQ][LK];       // scores -> weights
  __shared__ float s_po[2][TQ][D_];    // PV partials (2 k-chunks)

  for (int i = tid; i < TQ * H_; i += 256)
    s_q[i >> 7][i & 127] = qproj[(size_t)(b * LQ + q0 + (i >> 7)) * H_ + (i & 127)];
  if (tid < H_) s_wv[tid] = wv[tid];
  __syncthreads();
  int vlen = vlen_arr[b];

  const float4* wv4p = (const float4*)s_wv;

  // sum_wv (redundant per thread; broadcast LDS reads, once per block)
  float sum_wv = 0.f;
  #pragma unroll
  for (int j = 0; j < H_ / 4; ++j) {
    float4 t = wv4p[j];
    sum_wv += t.x + t.y + t.z + t.w;
  }

  // ---- scores: thread owns k column; skip masked-out waves entirely ----
  // score = sum_wv - 2 * sum_h wv_h / (exp(2(q_h+k_h)) + 1)   [tanh identity]
  for (int kbase = 0; kbase < LK; kbase += 256) {
    int k = kbase + tid;
    if (k < vlen) {
      const float4* krow = (const float4*)(kproj + ((size_t)b * LK + k) * H_);
      float acc[TQ];
      #pragma unroll
      for (int ql = 0; ql < TQ; ++ql) acc[ql] = 0.f;
      #pragma unroll 8
      for (int h4 = 0; h4 < H_ / 4; ++h4) {
        float4 kv = krow[h4];            // per-lane row, L1/L2 resident
        float4 w4 = wv4p[h4];            // LDS broadcast
        #pragma unroll
        for (int ql = 0; ql < TQ; ++ql) {
          float4 q4 = ((const float4*)s_q[ql])[h4];   // LDS broadcast
          // per element: v_add, v_exp, v_add, v_rcp, v_fmac  (5 instr)
          acc[ql] = fmaf(w4.x, frcp(fexp2(q4.x + kv.x) + 1.0f), acc[ql]);
          acc[ql] = fmaf(w4.y, frcp(fexp2(q4.y + kv.y) + 1.0f), acc[ql]);
          acc[ql] = fmaf(w4.z, frcp(fexp2(q4.z + kv.z) + 1.0f), acc[ql]);
          acc[ql] = fmaf(w4.w, frcp(fexp2(q4.w + kv.w) + 1.0f), acc[ql]);
        }
      }
      #pragma unroll
      for (int ql = 0; ql < TQ; ++ql)
        s_sc[ql][k] = fmaf(-2.0f, acc[ql], sum_wv);
    } else {
      #pragma unroll
      for (int ql = 0; ql < TQ; ++ql) s_sc[ql][k] = -1.0e6f;
    }
  }
  __syncthreads();

  int wave = tid >> 6, lane = tid & 63;

  // ---- masked softmax: wave w handles q-row w (waves >= TQ idle; cheap phase) ----
  if (wave < TQ) {
    float m = -3.0e38f;
    #pragma unroll
    for (int j = 0; j < LK / 64; ++j) m = fmaxf(m, s_sc[wave][lane + j * 64]);
    #pragma unroll
    for (int off = 32; off; off >>= 1) m = fmaxf(m, __shfl_xor(m, off));
    float sum = 0.f;
    float vals[LK / 64];
    #pragma unroll
    for (int j = 0; j < LK / 64; ++j) {
      float e = fexp2((s_sc[wave][lane + j * 64] - m) * LOG2E);  // masked -> 0
      vals[j] = e;
      sum += e;
    }
    #pragma unroll
    for (int off = 32; off; off >>= 1) sum += __shfl_xor(sum, off);
    float inv = frcp(sum);
    #pragma unroll
    for (int j = 0; j < LK / 64; ++j) s_sc[wave][lane + j * 64] = vals[j] * inv;
  }
  __syncthreads();

  // ---- PV: wave w -> (row = w>>1, k-chunk = w&1); float2 over d; k bounded by vlen ----
  {
    int row = wave >> 1, kc = wave & 1;
    int kend = min((((vlen + 3) >> 2) << 2), (kc + 1) * 256);
    const float2* vrow = (const float2*)(values + (size_t)b * LK * D_);
    float2 a = {0.f, 0.f};
    for (int k = kc * 256; k < kend; k += 4) {
      float4 sc4 = *((const float4*)&s_sc[row][k]);   // LDS broadcast
      float2 v0 = vrow[(size_t)(k + 0) * 64 + lane];  // 512B/wave coalesced
      float2 v1 = vrow[(size_t)(k + 1) * 64 + lane];
      float2 v2 = vrow[(size_t)(k + 2) * 64 + lane];
      float2 v3 = vrow[(size_t)(k + 3) * 64 + lane];
      a.x += sc4.x * v0.x + sc4.y * v1.x + sc4.z * v2.x + sc4.w * v3.x;
      a.y += sc4.x * v0.y + sc4.y * v1.y + sc4.z * v2.y + sc4.w * v3.y;
    }
    s_po[kc][row][2 * lane]     = a.x;
    s_po[kc][row][2 * lane + 1] = a.y;
  }
  __syncthreads();

  // ---- output projection: combine PV partials, project through Wo ----
  {
    int ql = tid >> 7, h = tid & 127;
    float acc = 0.f;
    #pragma unroll 8
    for (int d = 0; d < D_; ++d)
      acc += (s_po[0][ql][d] + s_po[1][ql][d]) * Wo[d * H_ + h];  // coalesced, L2-hot
    out[((size_t)b * LQ + q0 + ql) * H_ + h] = acc;
  }
}

extern "C" void kernel_launch(void* const* d_in, const int* in_sizes, int n_in,
                              void* d_out, int out_size, void* d_ws, size_t ws_size,
                              hipStream_t stream) {
  const float* queries = (const float*)d_in[0];
  const float* keys    = (const float*)d_in[1];
  const float* values  = (const float*)d_in[2];
  const int*   vlen    = (const int*)d_in[3];
  const float* Wq      = (const float*)d_in[4];
  const float* Wk      = (const float*)d_in[5];
  const float* wv      = (const float*)d_in[6];
  const float* Wo      = (const float*)d_in[7];
  float* out = (float*)d_out;

  float* qproj = (float*)d_ws;                       // 1 MB
  float* kproj = qproj + (size_t)B_ * LQ * H_;       // 1 MB

  proj_kernel<<<dim3(B_ * (LQ + LK) / 8), 256, 0, stream>>>(queries, keys, Wq, Wk, qproj, kproj);
  attn_kernel<<<dim3(LQ / TQ, B_), 256, 0, stream>>>(qproj, kproj, values, vlen, wv, Wo, out);
}